// Round 10
// baseline (442.452 us; speedup 1.0000x reference)
//
#include <hip/hip_runtime.h>
#include <hip/hip_bf16.h>

#define NEG_SLOPE 0.2f

typedef __attribute__((ext_vector_type(8))) short short8;   // 8 bf16 (4 VGPRs)
typedef __attribute__((ext_vector_type(4))) float f32x4;

__device__ __forceinline__ float wave_sum64(float v) {
#pragma unroll
    for (int off = 32; off >= 1; off >>= 1) v += __shfl_xor(v, off, 64);
    return v;
}

__device__ __forceinline__ float bf2f(unsigned short u) {
    return __uint_as_float((unsigned int)u << 16);
}

__device__ __forceinline__ unsigned short f2bf(float f) {
    __hip_bfloat16 hb = __float2bfloat16(f);   // RNE
    return *reinterpret_cast<unsigned short*>(&hb);
}

// ---------------------------------------------------------------------------
// CSR build: KB1 degree histogram -> KB2 unordered segment allocation
// (per-wave shfl scan + ONE atomicAdd per wave) -> KB3 scatter.
// ---------------------------------------------------------------------------
__global__ __launch_bounds__(256) void kb1_deg(
    const int* __restrict__ ei, int E, int Etot, int* __restrict__ deg) {
    int e = blockIdx.x * 256 + threadIdx.x;
    if (e >= Etot) return;
    int dst = (e < E) ? ei[E + e] : e - E;   // self-loops appended
    atomicAdd(&deg[dst], 1);
}

__global__ __launch_bounds__(256) void kb2_alloc(
    const int* __restrict__ deg, int N, int* __restrict__ counter,
    int* __restrict__ row_ptr, int* __restrict__ row_end,
    int* __restrict__ row_cur) {
    int n = blockIdx.x * 256 + threadIdx.x;
    int lane = threadIdx.x & 63;
    int d = (n < N) ? deg[n] : 0;
    int x = d;                                   // inclusive wave scan
#pragma unroll
    for (int off = 1; off < 64; off <<= 1) {
        int y = __shfl_up(x, off, 64);
        if (lane >= off) x += y;
    }
    int total = __shfl(x, 63, 64);
    int base = 0;
    if (lane == 63) base = atomicAdd(counter, total);
    base = __shfl(base, 63, 64);
    if (n < N) {
        int beg = base + x - d;
        row_ptr[n] = beg; row_cur[n] = beg; row_end[n] = beg + d;
    }
}

__global__ __launch_bounds__(256) void kb3_scatter(
    const int* __restrict__ ei, int E, int Etot,
    int* __restrict__ row_cur, int* __restrict__ csr_src) {
    int e = blockIdx.x * 256 + threadIdx.x;
    if (e >= Etot) return;
    int src, dst;
    if (e < E) { src = ei[e]; dst = ei[E + e]; }
    else       { src = dst = e - E; }
    int pos = atomicAdd(&row_cur[dst], 1);
    csr_src[pos] = src;
}

// ---------------------------------------------------------------------------
// KW: pack W2 [256,64] f32 -> W2t [64 cols][256 k] bf16.
// ---------------------------------------------------------------------------
__global__ __launch_bounds__(256) void kw_pack(
    const float* __restrict__ W2, unsigned short* __restrict__ W2t) {
    int i = blockIdx.x * 256 + threadIdx.x;   // grid 64 blocks
    if (i >= 64 * 256) return;
    int c = i >> 8, k = i & 255;
    W2t[c * 256 + k] = f2bf(W2[k * 64 + c]);
}

// ---------------------------------------------------------------------------
// K1: layer-1 node transform. One block (256 thr) per node.
// h in fp32; h1 stored bf16 head-interleaved h1b[n*256 + ch*4 + head].
// ---------------------------------------------------------------------------
__global__ __launch_bounds__(256) void k1_node1(
    const float* __restrict__ x, const float* __restrict__ W1,
    const float* __restrict__ a_src1, const float* __restrict__ a_dst1,
    unsigned short* __restrict__ h1b, float* __restrict__ al_s1,
    float* __restrict__ al_d1, int N) {
    int n = blockIdx.x;
    if (n >= N) return;
    int t = threadIdx.x;
    float h = 0.f;
#pragma unroll
    for (int k = 0; k < 5; ++k) h = fmaf(x[n * 5 + k], W1[k * 256 + t], h);
    int head = t >> 6, ch = t & 63;
    h1b[(size_t)n * 256 + ch * 4 + head] = f2bf(h);
    float s = wave_sum64(h * a_src1[t]);
    float d = wave_sum64(h * a_dst1[t]);
    if (ch == 0) {
        al_s1[n * 4 + head] = s;
        al_d1[n * 4 + head] = d;
    }
}

// ---------------------------------------------------------------------------
// K2a: layer-1 edge weights. One wave per dst node; LANES PARALLEL OVER EDGES
// (each edge's 4 exps computed ONCE, not 64x). Writes unnormalized ew[e][4]
// (f32x4, coalesced) + per-head denominators denom1[n][4] via wave reduce.
// Softmax max-shift elided (exact; logits O(1)).
// ---------------------------------------------------------------------------
__global__ __launch_bounds__(256) void k2a_wts(
    const int* __restrict__ csr_src, const int* __restrict__ row_ptr,
    const int* __restrict__ row_end, const float* __restrict__ al_s1,
    const float* __restrict__ al_d1, float* __restrict__ ew,
    float* __restrict__ denom1, int N) {
    int wave = threadIdx.x >> 6, lane = threadIdx.x & 63;
    int n = blockIdx.x * 4 + wave;
    if (n >= N) return;
    int beg = row_ptr[n], end = row_end[n];
    const float4 ad = *reinterpret_cast<const float4*>(&al_d1[n * 4]);
    float d0 = 0.f, d1 = 0.f, d2 = 0.f, d3 = 0.f;
    for (int base = beg; base < end; base += 64) {
        int e = base + lane;
        if (e < end) {
            int src = csr_src[e];
            const float4 as = *reinterpret_cast<const float4*>(&al_s1[src * 4]);
            float v0 = as.x + ad.x, v1 = as.y + ad.y, v2 = as.z + ad.z, v3 = as.w + ad.w;
            v0 = v0 > 0.f ? v0 : NEG_SLOPE * v0;
            v1 = v1 > 0.f ? v1 : NEG_SLOPE * v1;
            v2 = v2 > 0.f ? v2 : NEG_SLOPE * v2;
            v3 = v3 > 0.f ? v3 : NEG_SLOPE * v3;
            float4 ex;
            ex.x = __expf(v0); ex.y = __expf(v1); ex.z = __expf(v2); ex.w = __expf(v3);
            *reinterpret_cast<float4*>(&ew[(size_t)e * 4]) = ex;
            d0 += ex.x; d1 += ex.y; d2 += ex.z; d3 += ex.w;
        }
    }
    d0 = wave_sum64(d0); d1 = wave_sum64(d1);
    d2 = wave_sum64(d2); d3 = wave_sum64(d3);
    if (lane == 0) {
        float4 dn = {d0, d1, d2, d3};
        *reinterpret_cast<float4*>(&denom1[n * 4]) = dn;
    }
}

// ---------------------------------------------------------------------------
// K2b: layer-1 gather (pure fma). One wave per dst node; lane = channel.
// Per edge: shfl src + uniform 16B weight load + 8B h1b load + 4 bf2f + 4 fma.
// Epilogue: normalize + b1 + relu -> x2b (bf16 GEMM A-operand).
// ---------------------------------------------------------------------------
__global__ __launch_bounds__(256) void k2b_gather1(
    const int* __restrict__ csr_src, const int* __restrict__ row_ptr,
    const int* __restrict__ row_end, const unsigned short* __restrict__ h1b,
    const float* __restrict__ ew, const float* __restrict__ denom1,
    const float* __restrict__ b1, unsigned short* __restrict__ x2b, int N) {
    int wave = threadIdx.x >> 6, lane = threadIdx.x & 63;
    int n = blockIdx.x * 4 + wave;
    if (n >= N) return;
    int beg = row_ptr[n], end = row_end[n];
    float a0 = 0.f, a1 = 0.f, a2 = 0.f, a3 = 0.f;
    for (int base = beg; base < end; base += 64) {
        int nn = min(64, end - base);
        int srcv = (base + lane < end) ? csr_src[base + lane] : 0;
        for (int i = 0; i < nn; ++i) {
            int src = __shfl(srcv, i, 64);
            const float4 w = *reinterpret_cast<const float4*>(&ew[(size_t)(base + i) * 4]);
            const ushort4 u = *reinterpret_cast<const ushort4*>(
                &h1b[(size_t)src * 256 + lane * 4]);
            a0 = fmaf(w.x, bf2f(u.x), a0);
            a1 = fmaf(w.y, bf2f(u.y), a1);
            a2 = fmaf(w.z, bf2f(u.z), a2);
            a3 = fmaf(w.w, bf2f(u.w), a3);
        }
    }
    const float4 dn = *reinterpret_cast<const float4*>(&denom1[n * 4]);
    unsigned short* xo = &x2b[(size_t)n * 256];
    float r;
    r = a0 / dn.x + b1[0 * 64 + lane]; xo[0 * 64 + lane] = f2bf(r > 0.f ? r : 0.f);
    r = a1 / dn.y + b1[1 * 64 + lane]; xo[1 * 64 + lane] = f2bf(r > 0.f ? r : 0.f);
    r = a2 / dn.z + b1[2 * 64 + lane]; xo[2 * 64 + lane] = f2bf(r > 0.f ? r : 0.f);
    r = a3 / dn.w + b1[3 * 64 + lane]; xo[3 * 64 + lane] = f2bf(r > 0.f ? r : 0.f);
}

// ---------------------------------------------------------------------------
// K3 (MFMA): h2 = x2b @ W2, [N,256]@[256,64] bf16->f32. Unchanged from R8.
// ---------------------------------------------------------------------------
__global__ __launch_bounds__(256) void k3_mfma(
    const unsigned short* __restrict__ x2b, const unsigned short* __restrict__ W2t,
    const float* __restrict__ a_src2, const float* __restrict__ a_dst2,
    float* __restrict__ h2, float* __restrict__ al_s2, float* __restrict__ al_d2,
    int N) {
    int w = threadIdx.x >> 6, l = threadIdx.x & 63;
    int m0 = blockIdx.x * 64 + w * 16;
    if (m0 >= N) return;
    int lr = l & 15, lg = l >> 4;

    short8 b0[8], b1f[8], b2f[8], b3f[8];   // full W2 in regs (128 VGPR)
#pragma unroll
    for (int kk = 0; kk < 8; ++kk) {
        b0[kk]  = *reinterpret_cast<const short8*>(&W2t[(0 * 16 + lr) * 256 + kk * 32 + lg * 8]);
        b1f[kk] = *reinterpret_cast<const short8*>(&W2t[(1 * 16 + lr) * 256 + kk * 32 + lg * 8]);
        b2f[kk] = *reinterpret_cast<const short8*>(&W2t[(2 * 16 + lr) * 256 + kk * 32 + lg * 8]);
        b3f[kk] = *reinterpret_cast<const short8*>(&W2t[(3 * 16 + lr) * 256 + kk * 32 + lg * 8]);
    }
    short8 a[8];
#pragma unroll
    for (int kk = 0; kk < 8; ++kk)
        a[kk] = *reinterpret_cast<const short8*>(&x2b[(size_t)(m0 + lr) * 256 + kk * 32 + lg * 8]);

    f32x4 acc0 = {0.f, 0.f, 0.f, 0.f}, acc1 = acc0, acc2 = acc0, acc3 = acc0;
#pragma unroll
    for (int kk = 0; kk < 8; ++kk) {
        acc0 = __builtin_amdgcn_mfma_f32_16x16x32_bf16(a[kk], b0[kk],  acc0, 0, 0, 0);
        acc1 = __builtin_amdgcn_mfma_f32_16x16x32_bf16(a[kk], b1f[kk], acc1, 0, 0, 0);
        acc2 = __builtin_amdgcn_mfma_f32_16x16x32_bf16(a[kk], b2f[kk], acc2, 0, 0, 0);
        acc3 = __builtin_amdgcn_mfma_f32_16x16x32_bf16(a[kk], b3f[kk], acc3, 0, 0, 0);
    }

#pragma unroll
    for (int j = 0; j < 4; ++j) {
        float* hr = &h2[(size_t)(m0 + lg * 4 + j) * 64];
        hr[0 * 16 + lr] = acc0[j];
        hr[1 * 16 + lr] = acc1[j];
        hr[2 * 16 + lr] = acc2[j];
        hr[3 * 16 + lr] = acc3[j];
    }

    float sA0 = a_src2[0 * 16 + lr], sA1 = a_src2[1 * 16 + lr];
    float sA2 = a_src2[2 * 16 + lr], sA3 = a_src2[3 * 16 + lr];
    float sD0 = a_dst2[0 * 16 + lr], sD1 = a_dst2[1 * 16 + lr];
    float sD2 = a_dst2[2 * 16 + lr], sD3 = a_dst2[3 * 16 + lr];
    float p0 = acc0[0] * sA0 + acc1[0] * sA1 + acc2[0] * sA2 + acc3[0] * sA3;
    float p1 = acc0[1] * sA0 + acc1[1] * sA1 + acc2[1] * sA2 + acc3[1] * sA3;
    float p2 = acc0[2] * sA0 + acc1[2] * sA1 + acc2[2] * sA2 + acc3[2] * sA3;
    float p3 = acc0[3] * sA0 + acc1[3] * sA1 + acc2[3] * sA2 + acc3[3] * sA3;
    float q0 = acc0[0] * sD0 + acc1[0] * sD1 + acc2[0] * sD2 + acc3[0] * sD3;
    float q1 = acc0[1] * sD0 + acc1[1] * sD1 + acc2[1] * sD2 + acc3[1] * sD3;
    float q2 = acc0[2] * sD0 + acc1[2] * sD1 + acc2[2] * sD2 + acc3[2] * sD3;
    float q3 = acc0[3] * sD0 + acc1[3] * sD1 + acc2[3] * sD2 + acc3[3] * sD3;
#pragma unroll
    for (int off = 1; off <= 8; off <<= 1) {   // reduce within 16-lane group
        p0 += __shfl_xor(p0, off, 64); p1 += __shfl_xor(p1, off, 64);
        p2 += __shfl_xor(p2, off, 64); p3 += __shfl_xor(p3, off, 64);
        q0 += __shfl_xor(q0, off, 64); q1 += __shfl_xor(q1, off, 64);
        q2 += __shfl_xor(q2, off, 64); q3 += __shfl_xor(q3, off, 64);
    }
    if (lr == 0) {
        int r0 = m0 + lg * 4;
        al_s2[r0 + 0] = p0; al_s2[r0 + 1] = p1; al_s2[r0 + 2] = p2; al_s2[r0 + 3] = p3;
        al_d2[r0 + 0] = q0; al_d2[r0 + 1] = q1; al_d2[r0 + 2] = q2; al_d2[r0 + 3] = q3;
    }
}

// ---------------------------------------------------------------------------
// K4a: layer-2 edge weights. One wave per dst node; lanes parallel over edges.
// ---------------------------------------------------------------------------
__global__ __launch_bounds__(256) void k4a_wts(
    const int* __restrict__ csr_src, const int* __restrict__ row_ptr,
    const int* __restrict__ row_end, const float* __restrict__ al_s2,
    const float* __restrict__ al_d2, float* __restrict__ ew2,
    float* __restrict__ denom2, int N) {
    int wave = threadIdx.x >> 6, lane = threadIdx.x & 63;
    int n = blockIdx.x * 4 + wave;
    if (n >= N) return;
    int beg = row_ptr[n], end = row_end[n];
    float ad = al_d2[n];
    float dsum = 0.f;
    for (int base = beg; base < end; base += 64) {
        int e = base + lane;
        if (e < end) {
            int src = csr_src[e];
            float v = al_s2[src] + ad;
            v = v > 0.f ? v : NEG_SLOPE * v;
            float ex = __expf(v);
            ew2[e] = ex;
            dsum += ex;
        }
    }
    dsum = wave_sum64(dsum);
    if (lane == 0) denom2[n] = dsum;
}

// ---------------------------------------------------------------------------
// K4b: layer-2 gather (pure fma). One wave per dst; lane = channel.
// ---------------------------------------------------------------------------
__global__ __launch_bounds__(256) void k4b_gather2(
    const int* __restrict__ csr_src, const int* __restrict__ row_ptr,
    const int* __restrict__ row_end, const float* __restrict__ h2,
    const float* __restrict__ ew2, const float* __restrict__ denom2,
    float* __restrict__ o2, int N) {
    int wave = threadIdx.x >> 6, lane = threadIdx.x & 63;
    int n = blockIdx.x * 4 + wave;
    if (n >= N) return;
    int beg = row_ptr[n], end = row_end[n];
    float a = 0.f;
    for (int base = beg; base < end; base += 64) {
        int nn = min(64, end - base);
        int srcv = (base + lane < end) ? csr_src[base + lane] : 0;
        for (int i = 0; i < nn; ++i) {
            int src = __shfl(srcv, i, 64);
            float w = ew2[base + i];
            a = fmaf(w, h2[(size_t)src * 64 + lane], a);
        }
    }
    o2[(size_t)n * 64 + lane] = a / denom2[n];
}

// ---------------------------------------------------------------------------
// K5: node-mean + bias. Block = 1 wave, grid-stride over nodes.
// ---------------------------------------------------------------------------
__global__ __launch_bounds__(64) void k5_final(
    const float* __restrict__ o2, const float* __restrict__ b2,
    float* __restrict__ out, int N) {
    int lane = threadIdx.x;
    float acc = 0.f;
    for (int n = blockIdx.x; n < N; n += gridDim.x)
        acc += o2[(size_t)n * 64 + lane];
    float v = acc * (1.f / (float)N);
    if (blockIdx.x == 0) v += b2[lane];
    atomicAdd(&out[lane], v);
}

extern "C" void kernel_launch(void* const* d_in, const int* in_sizes, int n_in,
                              void* d_out, int out_size, void* d_ws, size_t ws_size,
                              hipStream_t stream) {
    const float* x   = (const float*)d_in[0];
    const int*   ei  = (const int*)d_in[1];
    const float* W1  = (const float*)d_in[2];
    const float* as1 = (const float*)d_in[3];
    const float* ad1 = (const float*)d_in[4];
    const float* b1  = (const float*)d_in[5];
    const float* W2  = (const float*)d_in[6];
    const float* as2 = (const float*)d_in[7];
    const float* ad2 = (const float*)d_in[8];
    const float* b2  = (const float*)d_in[9];
    float* out = (float*)d_out;

    const int F_in = in_sizes[2] / 256;        // W1: [F_in, 4*64]
    const int N = in_sizes[0] / F_in;
    const int E = in_sizes[1] / 2;
    const int Etot = E + N;

    // Workspace (~100 MB). Aliases: o2 = h1b (dead after K2b);
    // al_s2/al_d2 = al_s1/al_d1 (dead after K2a); ew2/denom2 = ew/denom1
    // (dead after K2b). All 16B-aligned (offsets are multiples of 16B).
    unsigned short* h1b = (unsigned short*)d_ws;        // N*256 us
    unsigned short* x2b = h1b + (size_t)N * 256;        // N*256 us
    float* h2    = (float*)(x2b + (size_t)N * 256);     // N*64 f32
    float* al_s1 = h2 + (size_t)N * 64;                 // N*4
    float* al_d1 = al_s1 + (size_t)N * 4;               // N*4
    float* ew    = al_d1 + (size_t)N * 4;               // Etot*4 f32
    float* denom1= ew + (size_t)Etot * 4;               // N*4
    unsigned short* W2t = (unsigned short*)(denom1 + (size_t)N * 4);  // 64*256 us
    int* deg     = (int*)(W2t + 64 * 256);              // N
    int* row_cur = deg + N;                             // N
    int* row_ptr = row_cur + N;                         // N
    int* row_end = row_ptr + N;                         // N
    int* counter = row_end + N;                         // 1
    int* csr_src = counter + 1;                         // Etot
    float* o2    = (float*)h1b;                         // alias, N*64 f32
    float* al_s2 = al_s1;                               // alias
    float* al_d2 = al_d1;                               // alias
    float* ew2   = ew;                                  // alias, Etot f32
    float* denom2= denom1;                              // alias, N f32

    hipMemsetAsync(deg, 0, (size_t)N * sizeof(int), stream);
    hipMemsetAsync(counter, 0, sizeof(int), stream);
    hipMemsetAsync(out, 0, 64 * sizeof(float), stream);

    kb1_deg    <<<(Etot + 255) / 256, 256, 0, stream>>>(ei, E, Etot, deg);
    kb2_alloc  <<<(N + 255) / 256, 256, 0, stream>>>(deg, N, counter, row_ptr, row_end, row_cur);
    kb3_scatter<<<(Etot + 255) / 256, 256, 0, stream>>>(ei, E, Etot, row_cur, csr_src);
    kw_pack    <<<64, 256, 0, stream>>>(W2, W2t);

    k1_node1   <<<N, 256, 0, stream>>>(x, W1, as1, ad1, h1b, al_s1, al_d1, N);
    k2a_wts    <<<(N + 3) / 4, 256, 0, stream>>>(csr_src, row_ptr, row_end, al_s1, al_d1, ew, denom1, N);
    k2b_gather1<<<(N + 3) / 4, 256, 0, stream>>>(csr_src, row_ptr, row_end, h1b, ew, denom1, b1, x2b, N);
    k3_mfma    <<<(N + 63) / 64, 256, 0, stream>>>(x2b, W2t, as2, ad2, h2, al_s2, al_d2, N);
    k4a_wts    <<<(N + 3) / 4, 256, 0, stream>>>(csr_src, row_ptr, row_end, al_s2, al_d2, ew2, denom2, N);
    k4b_gather2<<<(N + 3) / 4, 256, 0, stream>>>(csr_src, row_ptr, row_end, h2, ew2, denom2, o2, N);
    k5_final   <<<256, 64, 0, stream>>>(o2, b2, out, N);
}

// Round 15
// 400.405 us; speedup vs baseline: 1.1050x; 1.1050x over previous
//
#include <hip/hip_runtime.h>
#include <hip/hip_bf16.h>

#define NEG_SLOPE 0.2f

typedef __attribute__((ext_vector_type(8))) short short8;   // 8 bf16 (4 VGPRs)
typedef __attribute__((ext_vector_type(4))) float f32x4;

__device__ __forceinline__ float wave_sum64(float v) {
#pragma unroll
    for (int off = 32; off >= 1; off >>= 1) v += __shfl_xor(v, off, 64);
    return v;
}

__device__ __forceinline__ float bf2f(unsigned short u) {
    return __uint_as_float((unsigned int)u << 16);
}

__device__ __forceinline__ unsigned short f2bf(float f) {
    __hip_bfloat16 hb = __float2bfloat16(f);   // RNE
    return *reinterpret_cast<unsigned short*>(&hb);
}

// ---------------------------------------------------------------------------
// CSR build: KB1 degree histogram -> KB2 unordered segment allocation
// (per-wave shfl scan + ONE atomicAdd per wave) -> KB3 scatter.
// ---------------------------------------------------------------------------
__global__ __launch_bounds__(256) void kb1_deg(
    const int* __restrict__ ei, int E, int Etot, int* __restrict__ deg) {
    int e = blockIdx.x * 256 + threadIdx.x;
    if (e >= Etot) return;
    int dst = (e < E) ? ei[E + e] : e - E;   // self-loops appended
    atomicAdd(&deg[dst], 1);
}

__global__ __launch_bounds__(256) void kb2_alloc(
    const int* __restrict__ deg, int N, int* __restrict__ counter,
    int* __restrict__ row_ptr, int* __restrict__ row_end,
    int* __restrict__ row_cur) {
    int n = blockIdx.x * 256 + threadIdx.x;
    int lane = threadIdx.x & 63;
    int d = (n < N) ? deg[n] : 0;
    int x = d;                                   // inclusive wave scan
#pragma unroll
    for (int off = 1; off < 64; off <<= 1) {
        int y = __shfl_up(x, off, 64);
        if (lane >= off) x += y;
    }
    int total = __shfl(x, 63, 64);
    int base = 0;
    if (lane == 63) base = atomicAdd(counter, total);
    base = __shfl(base, 63, 64);
    if (n < N) {
        int beg = base + x - d;
        row_ptr[n] = beg; row_cur[n] = beg; row_end[n] = beg + d;
    }
}

__global__ __launch_bounds__(256) void kb3_scatter(
    const int* __restrict__ ei, int E, int Etot,
    int* __restrict__ row_cur, int* __restrict__ csr_src) {
    int e = blockIdx.x * 256 + threadIdx.x;
    if (e >= Etot) return;
    int src, dst;
    if (e < E) { src = ei[e]; dst = ei[E + e]; }
    else       { src = dst = e - E; }
    int pos = atomicAdd(&row_cur[dst], 1);
    csr_src[pos] = src;
}

// ---------------------------------------------------------------------------
// KW: pack W2 [256,64] f32 -> W2t [64 cols][256 k] bf16.
// ---------------------------------------------------------------------------
__global__ __launch_bounds__(256) void kw_pack(
    const float* __restrict__ W2, unsigned short* __restrict__ W2t) {
    int i = blockIdx.x * 256 + threadIdx.x;   // grid 64 blocks
    if (i >= 64 * 256) return;
    int c = i >> 8, k = i & 255;
    W2t[c * 256 + k] = f2bf(W2[k * 64 + c]);
}

// ---------------------------------------------------------------------------
// KPRE: contract W1 with attention vectors: Wa_s[f][h] = sum_c W1[f][h*64+c]*
// a_src1[h*64+c] (and Wa_d). Then al_s1 = x @ Wa_s — h1 NEVER materialized.
// One block, t = h*64+c, wave == head.
// ---------------------------------------------------------------------------
__global__ __launch_bounds__(256) void kpre(
    const float* __restrict__ W1, const float* __restrict__ a_src1,
    const float* __restrict__ a_dst1, float* __restrict__ Wa_s,
    float* __restrict__ Wa_d) {
    int t = threadIdx.x;
    int h = t >> 6;
    float a_s = a_src1[t], a_d = a_dst1[t];
#pragma unroll
    for (int f = 0; f < 5; ++f) {
        float w = W1[f * 256 + t];
        float ps = wave_sum64(w * a_s);
        float pd = wave_sum64(w * a_d);
        if ((t & 63) == 0) { Wa_s[f * 4 + h] = ps; Wa_d[f * 4 + h] = pd; }
    }
}

// ---------------------------------------------------------------------------
// K1': attention logits per node: al_s1[n][h] = sum_f x[n][f]*Wa_s[f][h].
// Thread per node; exact fp32 (identical to reference's h1-based al).
// ---------------------------------------------------------------------------
__global__ __launch_bounds__(256) void k1p(
    const float* __restrict__ x, const float* __restrict__ Wa_s,
    const float* __restrict__ Wa_d, float* __restrict__ al_s1,
    float* __restrict__ al_d1, int N) {
    int n = blockIdx.x * 256 + threadIdx.x;
    if (n >= N) return;
    float xv[5];
#pragma unroll
    for (int f = 0; f < 5; ++f) xv[f] = x[n * 5 + f];
    float4 s = {0.f, 0.f, 0.f, 0.f}, d = {0.f, 0.f, 0.f, 0.f};
#pragma unroll
    for (int f = 0; f < 5; ++f) {
        s.x = fmaf(xv[f], Wa_s[f * 4 + 0], s.x);
        s.y = fmaf(xv[f], Wa_s[f * 4 + 1], s.y);
        s.z = fmaf(xv[f], Wa_s[f * 4 + 2], s.z);
        s.w = fmaf(xv[f], Wa_s[f * 4 + 3], s.w);
        d.x = fmaf(xv[f], Wa_d[f * 4 + 0], d.x);
        d.y = fmaf(xv[f], Wa_d[f * 4 + 1], d.y);
        d.z = fmaf(xv[f], Wa_d[f * 4 + 2], d.z);
        d.w = fmaf(xv[f], Wa_d[f * 4 + 3], d.w);
    }
    *reinterpret_cast<float4*>(&al_s1[n * 4]) = s;
    *reinterpret_cast<float4*>(&al_d1[n * 4]) = d;
}

// ---------------------------------------------------------------------------
// K2 (fused, factored): per dst node aggregate 5-dim INPUT features:
// agg[h][f] = sum_e exp_h(e) * x[src_e][f]; denom[h] = sum_e exp_h(e).
// Then x2[n, h*64+c] = relu((agg[h]@W1[:,h*64+c]) / denom[h] + b1).
// Lanes parallel over edges (exp once per edge); 24 wave-reductions;
// epilogue lane = channel. Exact fp32 up to the single bf16 x2b store.
// Softmax max-shift elided (exact; logits O(1)).
// ---------------------------------------------------------------------------
__global__ __launch_bounds__(256) void k2_fused(
    const int* __restrict__ csr_src, const int* __restrict__ row_ptr,
    const int* __restrict__ row_end, const float* __restrict__ x,
    const float* __restrict__ al_s1, const float* __restrict__ al_d1,
    const float* __restrict__ W1, const float* __restrict__ b1,
    unsigned short* __restrict__ x2b, int N) {
    int wave = threadIdx.x >> 6, lane = threadIdx.x & 63;
    int n = blockIdx.x * 4 + wave;
    if (n >= N) return;
    int beg = row_ptr[n], end = row_end[n];
    const float4 ad = *reinterpret_cast<const float4*>(&al_d1[n * 4]);
    float agg[4][5];
#pragma unroll
    for (int h = 0; h < 4; ++h)
#pragma unroll
        for (int f = 0; f < 5; ++f) agg[h][f] = 0.f;
    float dn[4] = {0.f, 0.f, 0.f, 0.f};
    for (int base = beg; base < end; base += 64) {
        int e = base + lane;
        if (e < end) {
            int src = csr_src[e];
            const float4 as = *reinterpret_cast<const float4*>(&al_s1[src * 4]);
            float v0 = as.x + ad.x, v1 = as.y + ad.y, v2 = as.z + ad.z, v3 = as.w + ad.w;
            v0 = v0 > 0.f ? v0 : NEG_SLOPE * v0;
            v1 = v1 > 0.f ? v1 : NEG_SLOPE * v1;
            v2 = v2 > 0.f ? v2 : NEG_SLOPE * v2;
            v3 = v3 > 0.f ? v3 : NEG_SLOPE * v3;
            float ex[4];
            ex[0] = __expf(v0); ex[1] = __expf(v1); ex[2] = __expf(v2); ex[3] = __expf(v3);
            const float* xs = &x[(size_t)src * 5];
            float xv[5];
#pragma unroll
            for (int f = 0; f < 5; ++f) xv[f] = xs[f];
#pragma unroll
            for (int h = 0; h < 4; ++h) {
                dn[h] += ex[h];
#pragma unroll
                for (int f = 0; f < 5; ++f) agg[h][f] = fmaf(ex[h], xv[f], agg[h][f]);
            }
        }
    }
#pragma unroll
    for (int h = 0; h < 4; ++h) {
        dn[h] = wave_sum64(dn[h]);
#pragma unroll
        for (int f = 0; f < 5; ++f) agg[h][f] = wave_sum64(agg[h][f]);
    }
    unsigned short* xo = &x2b[(size_t)n * 256];
#pragma unroll
    for (int h = 0; h < 4; ++h) {
        float val = 0.f;
#pragma unroll
        for (int f = 0; f < 5; ++f)
            val = fmaf(agg[h][f], W1[f * 256 + h * 64 + lane], val);
        float r = val / dn[h] + b1[h * 64 + lane];
        xo[h * 64 + lane] = f2bf(r > 0.f ? r : 0.f);
    }
}

// ---------------------------------------------------------------------------
// K3 (MFMA): h2 = x2b @ W2, [N,256]@[256,64] bf16->f32; h2 stored BF16.
// Block = 4 waves = 64 rows; wave = 16-row M-tile, 4 N-tiles of 16 cols.
// al_s2/al_d2 fused from f32 accumulators (before rounding).
// ---------------------------------------------------------------------------
__global__ __launch_bounds__(256) void k3_mfma(
    const unsigned short* __restrict__ x2b, const unsigned short* __restrict__ W2t,
    const float* __restrict__ a_src2, const float* __restrict__ a_dst2,
    unsigned short* __restrict__ h2b, float* __restrict__ al_s2,
    float* __restrict__ al_d2, int N) {
    int w = threadIdx.x >> 6, l = threadIdx.x & 63;
    int m0 = blockIdx.x * 64 + w * 16;
    if (m0 >= N) return;
    int lr = l & 15, lg = l >> 4;

    short8 b0[8], b1f[8], b2f[8], b3f[8];   // full W2 in regs (128 VGPR)
#pragma unroll
    for (int kk = 0; kk < 8; ++kk) {
        b0[kk]  = *reinterpret_cast<const short8*>(&W2t[(0 * 16 + lr) * 256 + kk * 32 + lg * 8]);
        b1f[kk] = *reinterpret_cast<const short8*>(&W2t[(1 * 16 + lr) * 256 + kk * 32 + lg * 8]);
        b2f[kk] = *reinterpret_cast<const short8*>(&W2t[(2 * 16 + lr) * 256 + kk * 32 + lg * 8]);
        b3f[kk] = *reinterpret_cast<const short8*>(&W2t[(3 * 16 + lr) * 256 + kk * 32 + lg * 8]);
    }
    short8 a[8];
#pragma unroll
    for (int kk = 0; kk < 8; ++kk)
        a[kk] = *reinterpret_cast<const short8*>(&x2b[(size_t)(m0 + lr) * 256 + kk * 32 + lg * 8]);

    f32x4 acc0 = {0.f, 0.f, 0.f, 0.f}, acc1 = acc0, acc2 = acc0, acc3 = acc0;
#pragma unroll
    for (int kk = 0; kk < 8; ++kk) {
        acc0 = __builtin_amdgcn_mfma_f32_16x16x32_bf16(a[kk], b0[kk],  acc0, 0, 0, 0);
        acc1 = __builtin_amdgcn_mfma_f32_16x16x32_bf16(a[kk], b1f[kk], acc1, 0, 0, 0);
        acc2 = __builtin_amdgcn_mfma_f32_16x16x32_bf16(a[kk], b2f[kk], acc2, 0, 0, 0);
        acc3 = __builtin_amdgcn_mfma_f32_16x16x32_bf16(a[kk], b3f[kk], acc3, 0, 0, 0);
    }

#pragma unroll
    for (int j = 0; j < 4; ++j) {
        unsigned short* hr = &h2b[(size_t)(m0 + lg * 4 + j) * 64];
        hr[0 * 16 + lr] = f2bf(acc0[j]);
        hr[1 * 16 + lr] = f2bf(acc1[j]);
        hr[2 * 16 + lr] = f2bf(acc2[j]);
        hr[3 * 16 + lr] = f2bf(acc3[j]);
    }

    float sA0 = a_src2[0 * 16 + lr], sA1 = a_src2[1 * 16 + lr];
    float sA2 = a_src2[2 * 16 + lr], sA3 = a_src2[3 * 16 + lr];
    float sD0 = a_dst2[0 * 16 + lr], sD1 = a_dst2[1 * 16 + lr];
    float sD2 = a_dst2[2 * 16 + lr], sD3 = a_dst2[3 * 16 + lr];
    float p0 = acc0[0] * sA0 + acc1[0] * sA1 + acc2[0] * sA2 + acc3[0] * sA3;
    float p1 = acc0[1] * sA0 + acc1[1] * sA1 + acc2[1] * sA2 + acc3[1] * sA3;
    float p2 = acc0[2] * sA0 + acc1[2] * sA1 + acc2[2] * sA2 + acc3[2] * sA3;
    float p3 = acc0[3] * sA0 + acc1[3] * sA1 + acc2[3] * sA2 + acc3[3] * sA3;
    float q0 = acc0[0] * sD0 + acc1[0] * sD1 + acc2[0] * sD2 + acc3[0] * sD3;
    float q1 = acc0[1] * sD0 + acc1[1] * sD1 + acc2[1] * sD2 + acc3[1] * sD3;
    float q2 = acc0[2] * sD0 + acc1[2] * sD1 + acc2[2] * sD2 + acc3[2] * sD3;
    float q3 = acc0[3] * sD0 + acc1[3] * sD1 + acc2[3] * sD2 + acc3[3] * sD3;
#pragma unroll
    for (int off = 1; off <= 8; off <<= 1) {   // reduce within 16-lane group
        p0 += __shfl_xor(p0, off, 64); p1 += __shfl_xor(p1, off, 64);
        p2 += __shfl_xor(p2, off, 64); p3 += __shfl_xor(p3, off, 64);
        q0 += __shfl_xor(q0, off, 64); q1 += __shfl_xor(q1, off, 64);
        q2 += __shfl_xor(q2, off, 64); q3 += __shfl_xor(q3, off, 64);
    }
    if (lr == 0) {
        int r0 = m0 + lg * 4;
        al_s2[r0 + 0] = p0; al_s2[r0 + 1] = p1; al_s2[r0 + 2] = p2; al_s2[r0 + 3] = p3;
        al_d2[r0 + 0] = q0; al_d2[r0 + 1] = q1; al_d2[r0 + 2] = q2; al_d2[r0 + 3] = q3;
    }
}

// ---------------------------------------------------------------------------
// K4a: layer-2 edge weights. One wave per dst node; lanes parallel over edges.
// ---------------------------------------------------------------------------
__global__ __launch_bounds__(256) void k4a_wts(
    const int* __restrict__ csr_src, const int* __restrict__ row_ptr,
    const int* __restrict__ row_end, const float* __restrict__ al_s2,
    const float* __restrict__ al_d2, float* __restrict__ ew2,
    float* __restrict__ denom2, int N) {
    int wave = threadIdx.x >> 6, lane = threadIdx.x & 63;
    int n = blockIdx.x * 4 + wave;
    if (n >= N) return;
    int beg = row_ptr[n], end = row_end[n];
    float ad = al_d2[n];
    float dsum = 0.f;
    for (int base = beg; base < end; base += 64) {
        int e = base + lane;
        if (e < end) {
            int src = csr_src[e];
            float v = al_s2[src] + ad;
            v = v > 0.f ? v : NEG_SLOPE * v;
            float ex = __expf(v);
            ew2[e] = ex;
            dsum += ex;
        }
    }
    dsum = wave_sum64(dsum);
    if (lane == 0) denom2[n] = dsum;
}

// ---------------------------------------------------------------------------
// K4b: layer-2 gather (pure fma, bf16 h2 -> 128B/edge). One wave per dst;
// lane = channel.
// ---------------------------------------------------------------------------
__global__ __launch_bounds__(256) void k4b_gather2(
    const int* __restrict__ csr_src, const int* __restrict__ row_ptr,
    const int* __restrict__ row_end, const unsigned short* __restrict__ h2b,
    const float* __restrict__ ew2, const float* __restrict__ denom2,
    float* __restrict__ o2, int N) {
    int wave = threadIdx.x >> 6, lane = threadIdx.x & 63;
    int n = blockIdx.x * 4 + wave;
    if (n >= N) return;
    int beg = row_ptr[n], end = row_end[n];
    float a = 0.f;
    for (int base = beg; base < end; base += 64) {
        int nn = min(64, end - base);
        int srcv = (base + lane < end) ? csr_src[base + lane] : 0;
        for (int i = 0; i < nn; ++i) {
            int src = __shfl(srcv, i, 64);
            float w = ew2[base + i];
            a = fmaf(w, bf2f(h2b[(size_t)src * 64 + lane]), a);
        }
    }
    o2[(size_t)n * 64 + lane] = a / denom2[n];
}

// ---------------------------------------------------------------------------
// K5: node-mean + bias. Block = 1 wave, grid-stride over nodes.
// ---------------------------------------------------------------------------
__global__ __launch_bounds__(64) void k5_final(
    const float* __restrict__ o2, const float* __restrict__ b2,
    float* __restrict__ out, int N) {
    int lane = threadIdx.x;
    float acc = 0.f;
    for (int n = blockIdx.x; n < N; n += gridDim.x)
        acc += o2[(size_t)n * 64 + lane];
    float v = acc * (1.f / (float)N);
    if (blockIdx.x == 0) v += b2[lane];
    atomicAdd(&out[lane], v);
}

extern "C" void kernel_launch(void* const* d_in, const int* in_sizes, int n_in,
                              void* d_out, int out_size, void* d_ws, size_t ws_size,
                              hipStream_t stream) {
    const float* x   = (const float*)d_in[0];
    const int*   ei  = (const int*)d_in[1];
    const float* W1  = (const float*)d_in[2];
    const float* as1 = (const float*)d_in[3];
    const float* ad1 = (const float*)d_in[4];
    const float* b1  = (const float*)d_in[5];
    const float* W2  = (const float*)d_in[6];
    const float* as2 = (const float*)d_in[7];
    const float* ad2 = (const float*)d_in[8];
    const float* b2  = (const float*)d_in[9];
    float* out = (float*)d_out;

    const int F_in = in_sizes[2] / 256;        // W1: [F_in, 4*64]
    const int N = in_sizes[0] / F_in;
    const int E = in_sizes[1] / 2;
    const int Etot = E + N;

    // Workspace (~50 MB). Aliases: o2 = x2b space (dead after K3);
    // al_s2/al_d2 = al_s1/al_d1 (dead after K2). All 16B-aligned.
    unsigned short* x2b = (unsigned short*)d_ws;        // N*256 us
    unsigned short* h2b = x2b + (size_t)N * 256;        // N*64 us
    float* al_s1 = (float*)(h2b + (size_t)N * 64);      // N*4 f32
    float* al_d1 = al_s1 + (size_t)N * 4;               // N*4
    float* Wa_s  = al_d1 + (size_t)N * 4;               // 20 f32
    float* Wa_d  = Wa_s + 20;                           // 20 f32
    float* ew2   = Wa_d + 20;                           // Etot f32
    float* denom2= ew2 + (size_t)Etot;                  // N f32
    unsigned short* W2t = (unsigned short*)(denom2 + N);  // 64*256 us
    int* deg     = (int*)(W2t + 64 * 256);              // N
    int* row_cur = deg + N;                             // N
    int* row_ptr = row_cur + N;                         // N
    int* row_end = row_ptr + N;                         // N
    int* counter = row_end + N;                         // 1
    int* csr_src = counter + 1;                         // Etot
    float* o2    = (float*)x2b;                         // alias, N*64 f32
    float* al_s2 = al_s1;                               // alias
    float* al_d2 = al_d1;                               // alias

    hipMemsetAsync(deg, 0, (size_t)N * sizeof(int), stream);
    hipMemsetAsync(counter, 0, sizeof(int), stream);
    hipMemsetAsync(out, 0, 64 * sizeof(float), stream);

    kb1_deg    <<<(Etot + 255) / 256, 256, 0, stream>>>(ei, E, Etot, deg);
    kb2_alloc  <<<(N + 255) / 256, 256, 0, stream>>>(deg, N, counter, row_ptr, row_end, row_cur);
    kb3_scatter<<<(Etot + 255) / 256, 256, 0, stream>>>(ei, E, Etot, row_cur, csr_src);
    kw_pack    <<<64, 256, 0, stream>>>(W2, W2t);
    kpre       <<<1, 256, 0, stream>>>(W1, as1, ad1, Wa_s, Wa_d);

    k1p        <<<(N + 255) / 256, 256, 0, stream>>>(x, Wa_s, Wa_d, al_s1, al_d1, N);
    k2_fused   <<<(N + 3) / 4, 256, 0, stream>>>(csr_src, row_ptr, row_end, x, al_s1, al_d1, W1, b1, x2b, N);
    k3_mfma    <<<(N + 63) / 64, 256, 0, stream>>>(x2b, W2t, as2, ad2, h2b, al_s2, al_d2, N);
    k4a_wts    <<<(N + 3) / 4, 256, 0, stream>>>(csr_src, row_ptr, row_end, al_s2, al_d2, ew2, denom2, N);
    k4b_gather2<<<(N + 3) / 4, 256, 0, stream>>>(csr_src, row_ptr, row_end, h2b, ew2, denom2, o2, N);
    k5_final   <<<256, 64, 0, stream>>>(o2, b2, out, N);
}

// Round 16
// 357.569 us; speedup vs baseline: 1.2374x; 1.1198x over previous
//
#include <hip/hip_runtime.h>
#include <hip/hip_bf16.h>

#define NEG_SLOPE 0.2f

typedef __attribute__((ext_vector_type(8))) short short8;   // 8 bf16 (4 VGPRs)
typedef __attribute__((ext_vector_type(4))) float f32x4;

__device__ __forceinline__ float wave_sum64(float v) {
#pragma unroll
    for (int off = 32; off >= 1; off >>= 1) v += __shfl_xor(v, off, 64);
    return v;
}

__device__ __forceinline__ float bf2f(unsigned short u) {
    return __uint_as_float((unsigned int)u << 16);
}

__device__ __forceinline__ unsigned short f2bf(float f) {
    __hip_bfloat16 hb = __float2bfloat16(f);   // RNE
    return *reinterpret_cast<unsigned short*>(&hb);
}

// ---------------------------------------------------------------------------
// CSR build: KB1 degree histogram -> KB2 unordered segment allocation
// (per-wave shfl scan + ONE atomicAdd per wave) -> KB3 scatter.
// ---------------------------------------------------------------------------
__global__ __launch_bounds__(256) void kb1_deg(
    const int* __restrict__ ei, int E, int Etot, int* __restrict__ deg) {
    int e = blockIdx.x * 256 + threadIdx.x;
    if (e >= Etot) return;
    int dst = (e < E) ? ei[E + e] : e - E;   // self-loops appended
    atomicAdd(&deg[dst], 1);
}

__global__ __launch_bounds__(256) void kb2_alloc(
    const int* __restrict__ deg, int N, int* __restrict__ counter,
    int* __restrict__ row_ptr, int* __restrict__ row_end,
    int* __restrict__ row_cur) {
    int n = blockIdx.x * 256 + threadIdx.x;
    int lane = threadIdx.x & 63;
    int d = (n < N) ? deg[n] : 0;
    int x = d;                                   // inclusive wave scan
#pragma unroll
    for (int off = 1; off < 64; off <<= 1) {
        int y = __shfl_up(x, off, 64);
        if (lane >= off) x += y;
    }
    int total = __shfl(x, 63, 64);
    int base = 0;
    if (lane == 63) base = atomicAdd(counter, total);
    base = __shfl(base, 63, 64);
    if (n < N) {
        int beg = base + x - d;
        row_ptr[n] = beg; row_cur[n] = beg; row_end[n] = beg + d;
    }
}

__global__ __launch_bounds__(256) void kb3_scatter(
    const int* __restrict__ ei, int E, int Etot,
    int* __restrict__ row_cur, int* __restrict__ csr_src) {
    int e = blockIdx.x * 256 + threadIdx.x;
    if (e >= Etot) return;
    int src, dst;
    if (e < E) { src = ei[e]; dst = ei[E + e]; }
    else       { src = dst = e - E; }
    int pos = atomicAdd(&row_cur[dst], 1);
    csr_src[pos] = src;
}

// ---------------------------------------------------------------------------
// KW: pack W2 [256,64] f32 -> W2t [64 cols][256 k] bf16.
// ---------------------------------------------------------------------------
__global__ __launch_bounds__(256) void kw_pack(
    const float* __restrict__ W2, unsigned short* __restrict__ W2t) {
    int i = blockIdx.x * 256 + threadIdx.x;   // grid 64 blocks
    if (i >= 64 * 256) return;
    int c = i >> 8, k = i & 255;
    W2t[c * 256 + k] = f2bf(W2[k * 64 + c]);
}

// ---------------------------------------------------------------------------
// KPRE: contract W1 with attention vectors: Wa_s[f][h] = sum_c W1[f][h*64+c]*
// a_src1[h*64+c] (and Wa_d). Then al_s1 = x @ Wa_s — h1 NEVER materialized.
// ---------------------------------------------------------------------------
__global__ __launch_bounds__(256) void kpre(
    const float* __restrict__ W1, const float* __restrict__ a_src1,
    const float* __restrict__ a_dst1, float* __restrict__ Wa_s,
    float* __restrict__ Wa_d) {
    int t = threadIdx.x;
    int h = t >> 6;
    float a_s = a_src1[t], a_d = a_dst1[t];
#pragma unroll
    for (int f = 0; f < 5; ++f) {
        float w = W1[f * 256 + t];
        float ps = wave_sum64(w * a_s);
        float pd = wave_sum64(w * a_d);
        if ((t & 63) == 0) { Wa_s[f * 4 + h] = ps; Wa_d[f * 4 + h] = pd; }
    }
}

// ---------------------------------------------------------------------------
// K1': attention logits per node: al_s1[n][h] = sum_f x[n][f]*Wa_s[f][h].
// ---------------------------------------------------------------------------
__global__ __launch_bounds__(256) void k1p(
    const float* __restrict__ x, const float* __restrict__ Wa_s,
    const float* __restrict__ Wa_d, float* __restrict__ al_s1,
    float* __restrict__ al_d1, int N) {
    int n = blockIdx.x * 256 + threadIdx.x;
    if (n >= N) return;
    float xv[5];
#pragma unroll
    for (int f = 0; f < 5; ++f) xv[f] = x[n * 5 + f];
    float4 s = {0.f, 0.f, 0.f, 0.f}, d = {0.f, 0.f, 0.f, 0.f};
#pragma unroll
    for (int f = 0; f < 5; ++f) {
        s.x = fmaf(xv[f], Wa_s[f * 4 + 0], s.x);
        s.y = fmaf(xv[f], Wa_s[f * 4 + 1], s.y);
        s.z = fmaf(xv[f], Wa_s[f * 4 + 2], s.z);
        s.w = fmaf(xv[f], Wa_s[f * 4 + 3], s.w);
        d.x = fmaf(xv[f], Wa_d[f * 4 + 0], d.x);
        d.y = fmaf(xv[f], Wa_d[f * 4 + 1], d.y);
        d.z = fmaf(xv[f], Wa_d[f * 4 + 2], d.z);
        d.w = fmaf(xv[f], Wa_d[f * 4 + 3], d.w);
    }
    *reinterpret_cast<float4*>(&al_s1[n * 4]) = s;
    *reinterpret_cast<float4*>(&al_d1[n * 4]) = d;
}

// ---------------------------------------------------------------------------
// K2 (fused, factored, 16-LANE GROUPS): 4 nodes per wave; group g = node.
// Edge loop strides 16 (deg~17 -> ~60% lane util vs 27% at 64-wide).
// Butterfly reduce 24 values over offsets {1,2,4,8}: 24 shfl/node (was 144),
// and every lane of the group ends with the sums -> zero-broadcast epilogue:
// 16 iters/group write all 256 channels. Exact fp32 up to bf16 x2b store.
// ---------------------------------------------------------------------------
__global__ __launch_bounds__(256) void k2_fused(
    const int* __restrict__ csr_src, const int* __restrict__ row_ptr,
    const int* __restrict__ row_end, const float* __restrict__ x,
    const float* __restrict__ al_s1, const float* __restrict__ al_d1,
    const float* __restrict__ W1, const float* __restrict__ b1,
    unsigned short* __restrict__ x2b, int N) {
    int wave = threadIdx.x >> 6, lane = threadIdx.x & 63;
    int g = lane >> 4, gl = lane & 15;
    int n = blockIdx.x * 16 + wave * 4 + g;
    bool valid = (n < N);
    int beg = valid ? row_ptr[n] : 0;
    int end = valid ? row_end[n] : 0;
    float4 ad = {0.f, 0.f, 0.f, 0.f};
    if (valid) ad = *reinterpret_cast<const float4*>(&al_d1[n * 4]);
    float agg[4][5];
#pragma unroll
    for (int h = 0; h < 4; ++h)
#pragma unroll
        for (int f = 0; f < 5; ++f) agg[h][f] = 0.f;
    float dn[4] = {0.f, 0.f, 0.f, 0.f};
    for (int base = beg; base < end; base += 16) {
        int e = base + gl;
        if (e < end) {
            int src = csr_src[e];
            const float4 as = *reinterpret_cast<const float4*>(&al_s1[src * 4]);
            float v0 = as.x + ad.x, v1 = as.y + ad.y, v2 = as.z + ad.z, v3 = as.w + ad.w;
            v0 = v0 > 0.f ? v0 : NEG_SLOPE * v0;
            v1 = v1 > 0.f ? v1 : NEG_SLOPE * v1;
            v2 = v2 > 0.f ? v2 : NEG_SLOPE * v2;
            v3 = v3 > 0.f ? v3 : NEG_SLOPE * v3;
            float ex[4];
            ex[0] = __expf(v0); ex[1] = __expf(v1); ex[2] = __expf(v2); ex[3] = __expf(v3);
            const float* xs = &x[(size_t)src * 5];
            float xv[5];
#pragma unroll
            for (int f = 0; f < 5; ++f) xv[f] = xs[f];
#pragma unroll
            for (int h = 0; h < 4; ++h) {
                dn[h] += ex[h];
#pragma unroll
                for (int f = 0; f < 5; ++f) agg[h][f] = fmaf(ex[h], xv[f], agg[h][f]);
            }
        }
    }
    // butterfly reduce within the 16-lane group; all 16 lanes get the sums
#pragma unroll
    for (int off = 1; off <= 8; off <<= 1) {
#pragma unroll
        for (int h = 0; h < 4; ++h) {
            dn[h] += __shfl_xor(dn[h], off, 64);
#pragma unroll
            for (int f = 0; f < 5; ++f) agg[h][f] += __shfl_xor(agg[h][f], off, 64);
        }
    }
    if (!valid) return;
    unsigned short* xo = &x2b[(size_t)n * 256];
    float rdn[4] = {1.f / dn[0], 1.f / dn[1], 1.f / dn[2], 1.f / dn[3]};
#pragma unroll
    for (int h = 0; h < 4; ++h) {
#pragma unroll
        for (int cj = 0; cj < 4; ++cj) {
            int c = cj * 16 + gl;
            float val = 0.f;
#pragma unroll
            for (int f = 0; f < 5; ++f)
                val = fmaf(agg[h][f], W1[f * 256 + h * 64 + c], val);
            float r = fmaf(val, rdn[h], b1[h * 64 + c]);
            xo[h * 64 + c] = f2bf(r > 0.f ? r : 0.f);
        }
    }
}

// ---------------------------------------------------------------------------
// K3 (MFMA): h2 = x2b @ W2, [N,256]@[256,64] bf16->f32; h2 stored BF16.
// ---------------------------------------------------------------------------
__global__ __launch_bounds__(256) void k3_mfma(
    const unsigned short* __restrict__ x2b, const unsigned short* __restrict__ W2t,
    const float* __restrict__ a_src2, const float* __restrict__ a_dst2,
    unsigned short* __restrict__ h2b, float* __restrict__ al_s2,
    float* __restrict__ al_d2, int N) {
    int w = threadIdx.x >> 6, l = threadIdx.x & 63;
    int m0 = blockIdx.x * 64 + w * 16;
    if (m0 >= N) return;
    int lr = l & 15, lg = l >> 4;

    short8 b0[8], b1f[8], b2f[8], b3f[8];   // full W2 in regs (128 VGPR)
#pragma unroll
    for (int kk = 0; kk < 8; ++kk) {
        b0[kk]  = *reinterpret_cast<const short8*>(&W2t[(0 * 16 + lr) * 256 + kk * 32 + lg * 8]);
        b1f[kk] = *reinterpret_cast<const short8*>(&W2t[(1 * 16 + lr) * 256 + kk * 32 + lg * 8]);
        b2f[kk] = *reinterpret_cast<const short8*>(&W2t[(2 * 16 + lr) * 256 + kk * 32 + lg * 8]);
        b3f[kk] = *reinterpret_cast<const short8*>(&W2t[(3 * 16 + lr) * 256 + kk * 32 + lg * 8]);
    }
    short8 a[8];
#pragma unroll
    for (int kk = 0; kk < 8; ++kk)
        a[kk] = *reinterpret_cast<const short8*>(&x2b[(size_t)(m0 + lr) * 256 + kk * 32 + lg * 8]);

    f32x4 acc0 = {0.f, 0.f, 0.f, 0.f}, acc1 = acc0, acc2 = acc0, acc3 = acc0;
#pragma unroll
    for (int kk = 0; kk < 8; ++kk) {
        acc0 = __builtin_amdgcn_mfma_f32_16x16x32_bf16(a[kk], b0[kk],  acc0, 0, 0, 0);
        acc1 = __builtin_amdgcn_mfma_f32_16x16x32_bf16(a[kk], b1f[kk], acc1, 0, 0, 0);
        acc2 = __builtin_amdgcn_mfma_f32_16x16x32_bf16(a[kk], b2f[kk], acc2, 0, 0, 0);
        acc3 = __builtin_amdgcn_mfma_f32_16x16x32_bf16(a[kk], b3f[kk], acc3, 0, 0, 0);
    }

#pragma unroll
    for (int j = 0; j < 4; ++j) {
        unsigned short* hr = &h2b[(size_t)(m0 + lg * 4 + j) * 64];
        hr[0 * 16 + lr] = f2bf(acc0[j]);
        hr[1 * 16 + lr] = f2bf(acc1[j]);
        hr[2 * 16 + lr] = f2bf(acc2[j]);
        hr[3 * 16 + lr] = f2bf(acc3[j]);
    }

    float sA0 = a_src2[0 * 16 + lr], sA1 = a_src2[1 * 16 + lr];
    float sA2 = a_src2[2 * 16 + lr], sA3 = a_src2[3 * 16 + lr];
    float sD0 = a_dst2[0 * 16 + lr], sD1 = a_dst2[1 * 16 + lr];
    float sD2 = a_dst2[2 * 16 + lr], sD3 = a_dst2[3 * 16 + lr];
    float p0 = acc0[0] * sA0 + acc1[0] * sA1 + acc2[0] * sA2 + acc3[0] * sA3;
    float p1 = acc0[1] * sA0 + acc1[1] * sA1 + acc2[1] * sA2 + acc3[1] * sA3;
    float p2 = acc0[2] * sA0 + acc1[2] * sA1 + acc2[2] * sA2 + acc3[2] * sA3;
    float p3 = acc0[3] * sA0 + acc1[3] * sA1 + acc2[3] * sA2 + acc3[3] * sA3;
    float q0 = acc0[0] * sD0 + acc1[0] * sD1 + acc2[0] * sD2 + acc3[0] * sD3;
    float q1 = acc0[1] * sD0 + acc1[1] * sD1 + acc2[1] * sD2 + acc3[1] * sD3;
    float q2 = acc0[2] * sD0 + acc1[2] * sD1 + acc2[2] * sD2 + acc3[2] * sD3;
    float q3 = acc0[3] * sD0 + acc1[3] * sD1 + acc2[3] * sD2 + acc3[3] * sD3;
#pragma unroll
    for (int off = 1; off <= 8; off <<= 1) {   // reduce within 16-lane group
        p0 += __shfl_xor(p0, off, 64); p1 += __shfl_xor(p1, off, 64);
        p2 += __shfl_xor(p2, off, 64); p3 += __shfl_xor(p3, off, 64);
        q0 += __shfl_xor(q0, off, 64); q1 += __shfl_xor(q1, off, 64);
        q2 += __shfl_xor(q2, off, 64); q3 += __shfl_xor(q3, off, 64);
    }
    if (lr == 0) {
        int r0 = m0 + lg * 4;
        al_s2[r0 + 0] = p0; al_s2[r0 + 1] = p1; al_s2[r0 + 2] = p2; al_s2[r0 + 3] = p3;
        al_d2[r0 + 0] = q0; al_d2[r0 + 1] = q1; al_d2[r0 + 2] = q2; al_d2[r0 + 3] = q3;
    }
}

// ---------------------------------------------------------------------------
// K4a: layer-2 edge weights. One wave per dst node; lanes parallel over edges.
// ---------------------------------------------------------------------------
__global__ __launch_bounds__(256) void k4a_wts(
    const int* __restrict__ csr_src, const int* __restrict__ row_ptr,
    const int* __restrict__ row_end, const float* __restrict__ al_s2,
    const float* __restrict__ al_d2, float* __restrict__ ew2,
    float* __restrict__ denom2, int N) {
    int wave = threadIdx.x >> 6, lane = threadIdx.x & 63;
    int n = blockIdx.x * 4 + wave;
    if (n >= N) return;
    int beg = row_ptr[n], end = row_end[n];
    float ad = al_d2[n];
    float dsum = 0.f;
    for (int base = beg; base < end; base += 64) {
        int e = base + lane;
        if (e < end) {
            int src = csr_src[e];
            float v = al_s2[src] + ad;
            v = v > 0.f ? v : NEG_SLOPE * v;
            float ex = __expf(v);
            ew2[e] = ex;
            dsum += ex;
        }
    }
    dsum = wave_sum64(dsum);
    if (lane == 0) denom2[n] = dsum;
}

// ---------------------------------------------------------------------------
// K4b: layer-2 gather (pure fma, bf16 h2 -> 128B/edge). One wave per dst;
// lane = channel.
// ---------------------------------------------------------------------------
__global__ __launch_bounds__(256) void k4b_gather2(
    const int* __restrict__ csr_src, const int* __restrict__ row_ptr,
    const int* __restrict__ row_end, const unsigned short* __restrict__ h2b,
    const float* __restrict__ ew2, const float* __restrict__ denom2,
    float* __restrict__ o2, int N) {
    int wave = threadIdx.x >> 6, lane = threadIdx.x & 63;
    int n = blockIdx.x * 4 + wave;
    if (n >= N) return;
    int beg = row_ptr[n], end = row_end[n];
    float a = 0.f;
    for (int base = beg; base < end; base += 64) {
        int nn = min(64, end - base);
        int srcv = (base + lane < end) ? csr_src[base + lane] : 0;
        for (int i = 0; i < nn; ++i) {
            int src = __shfl(srcv, i, 64);
            float w = ew2[base + i];
            a = fmaf(w, bf2f(h2b[(size_t)src * 64 + lane]), a);
        }
    }
    o2[(size_t)n * 64 + lane] = a / denom2[n];
}

// ---------------------------------------------------------------------------
// K5: node-mean + bias. Block = 1 wave, grid-stride over nodes.
// ---------------------------------------------------------------------------
__global__ __launch_bounds__(64) void k5_final(
    const float* __restrict__ o2, const float* __restrict__ b2,
    float* __restrict__ out, int N) {
    int lane = threadIdx.x;
    float acc = 0.f;
    for (int n = blockIdx.x; n < N; n += gridDim.x)
        acc += o2[(size_t)n * 64 + lane];
    float v = acc * (1.f / (float)N);
    if (blockIdx.x == 0) v += b2[lane];
    atomicAdd(&out[lane], v);
}

extern "C" void kernel_launch(void* const* d_in, const int* in_sizes, int n_in,
                              void* d_out, int out_size, void* d_ws, size_t ws_size,
                              hipStream_t stream) {
    const float* x   = (const float*)d_in[0];
    const int*   ei  = (const int*)d_in[1];
    const float* W1  = (const float*)d_in[2];
    const float* as1 = (const float*)d_in[3];
    const float* ad1 = (const float*)d_in[4];
    const float* b1  = (const float*)d_in[5];
    const float* W2  = (const float*)d_in[6];
    const float* as2 = (const float*)d_in[7];
    const float* ad2 = (const float*)d_in[8];
    const float* b2  = (const float*)d_in[9];
    float* out = (float*)d_out;

    const int F_in = in_sizes[2] / 256;        // W1: [F_in, 4*64]
    const int N = in_sizes[0] / F_in;
    const int E = in_sizes[1] / 2;
    const int Etot = E + N;

    // Workspace (~50 MB). Aliases: o2 = x2b space (dead after K3);
    // al_s2/al_d2 = al_s1/al_d1 (dead after K2). All 16B-aligned.
    unsigned short* x2b = (unsigned short*)d_ws;        // N*256 us
    unsigned short* h2b = x2b + (size_t)N * 256;        // N*64 us
    float* al_s1 = (float*)(h2b + (size_t)N * 64);      // N*4 f32
    float* al_d1 = al_s1 + (size_t)N * 4;               // N*4
    float* Wa_s  = al_d1 + (size_t)N * 4;               // 20 f32
    float* Wa_d  = Wa_s + 20;                           // 20 f32
    float* ew2   = Wa_d + 20;                           // Etot f32
    float* denom2= ew2 + (size_t)Etot;                  // N f32
    unsigned short* W2t = (unsigned short*)(denom2 + N);  // 64*256 us
    int* deg     = (int*)(W2t + 64 * 256);              // N
    int* row_cur = deg + N;                             // N
    int* row_ptr = row_cur + N;                         // N
    int* row_end = row_ptr + N;                         // N
    int* counter = row_end + N;                         // 1
    int* csr_src = counter + 1;                         // Etot
    float* o2    = (float*)x2b;                         // alias, N*64 f32
    float* al_s2 = al_s1;                               // alias
    float* al_d2 = al_d1;                               // alias

    hipMemsetAsync(deg, 0, (size_t)N * sizeof(int), stream);
    hipMemsetAsync(counter, 0, sizeof(int), stream);
    hipMemsetAsync(out, 0, 64 * sizeof(float), stream);

    kb1_deg    <<<(Etot + 255) / 256, 256, 0, stream>>>(ei, E, Etot, deg);
    kb2_alloc  <<<(N + 255) / 256, 256, 0, stream>>>(deg, N, counter, row_ptr, row_end, row_cur);
    kb3_scatter<<<(Etot + 255) / 256, 256, 0, stream>>>(ei, E, Etot, row_cur, csr_src);
    kw_pack    <<<64, 256, 0, stream>>>(W2, W2t);
    kpre       <<<1, 256, 0, stream>>>(W1, as1, ad1, Wa_s, Wa_d);

    k1p        <<<(N + 255) / 256, 256, 0, stream>>>(x, Wa_s, Wa_d, al_s1, al_d1, N);
    k2_fused   <<<(N + 15) / 16, 256, 0, stream>>>(csr_src, row_ptr, row_end, x, al_s1, al_d1, W1, b1, x2b, N);
    k3_mfma    <<<(N + 63) / 64, 256, 0, stream>>>(x2b, W2t, as2, ad2, h2b, al_s2, al_d2, N);
    k4a_wts    <<<(N + 3) / 4, 256, 0, stream>>>(csr_src, row_ptr, row_end, al_s2, al_d2, ew2, denom2, N);
    k4b_gather2<<<(N + 3) / 4, 256, 0, stream>>>(csr_src, row_ptr, row_end, h2b, ew2, denom2, o2, N);
    k5_final   <<<256, 64, 0, stream>>>(o2, b2, out, N);
}